// Round 16
// baseline (1190.091 us; speedup 1.0000x reference)
//
#include <hip/hip_runtime.h>
#include <stdint.h>

// Problem constants
#define Bn   2
#define Sn   4096
#define NQn  576
#define Hn   32
#define HDn  128
#define HIDn 4096

typedef unsigned short bfu;  // raw bf16 bits
typedef short short8 __attribute__((ext_vector_type(8)));
typedef float f32x4 __attribute__((ext_vector_type(4)));

__device__ __forceinline__ bfu f2b(float f) {
  uint32_t x = __builtin_bit_cast(uint32_t, f);
  return (bfu)((x + 0x7fffu + ((x >> 16) & 1u)) >> 16);  // RNE
}

__device__ __forceinline__ void gload16(const void* g, void* l) {
  // async global->LDS, 16B per lane; LDS dest = wave-uniform base + lane*16
  __builtin_amdgcn_global_load_lds(
      (const __attribute__((address_space(1))) uint32_t*)g,
      (__attribute__((address_space(3))) uint32_t*)l, 16, 0, 0);
}

__device__ __forceinline__ void cast8(const float* s, bfu* d, long i) {
  const float4* in4 = (const float4*)s;
  float4 a = in4[2 * i], c = in4[2 * i + 1];
  short8 v;
  v[0] = (short)f2b(a.x); v[1] = (short)f2b(a.y);
  v[2] = (short)f2b(a.z); v[3] = (short)f2b(a.w);
  v[4] = (short)f2b(c.x); v[5] = (short)f2b(c.y);
  v[6] = (short)f2b(c.z); v[7] = (short)f2b(c.w);
  ((short8*)d)[i] = v;
}

// ---------------- cast f32 -> bf16 (single input) ------------------------------
__global__ void cast_f32_bf16(const float* __restrict__ in, bfu* __restrict__ out,
                              int n8) {
  long i = (long)blockIdx.x * 256 + threadIdx.x;
  if (i >= n8) return;
  cast8(in, out, i);
}

// ---------------- fused 5-input cast (one launch; all n8 divide 256) -----------
__global__ void cast5(const float* s0, bfu* d0, int n0, const float* s1, bfu* d1,
                      int n1, const float* s2, bfu* d2, int n2, const float* s3,
                      bfu* d3, int n3, const float* s4, bfu* d4, int n4) {
  long gid = (long)blockIdx.x * 256 + threadIdx.x;
  if (gid < n0) { cast8(s0, d0, gid); return; }
  gid -= n0;
  if (gid < n1) { cast8(s1, d1, gid); return; }
  gid -= n1;
  if (gid < n2) { cast8(s2, d2, gid); return; }
  gid -= n2;
  if (gid < n3) { cast8(s3, d3, gid); return; }
  gid -= n3;
  if (gid < n4) cast8(s4, d4, gid);
}

// ======== 256^2 GEMM, merged-region 4-barrier schedule: C = A @ Bm^T ==========
// R15 (8 barriers/tile, reads|barrier|lgkmcnt(0)|MFMA lockstep) = 287us,
// MfmaUtil 41.5% -- LDS pipe idle during every MFMA cluster (wall = LDS 2304
// + MFMA 2483 + barriers, additive). R16: merge each pre/mfma pair -- issue
// the NEXT quadrant's ds_reads BEFORE the current quadrant's MFMAs, so the
// LDS queue services them under the matrix pipe (within-wave ILP), and
// barriers drop 8 -> 4 per tile. Per tile:
//   R0: read a0(8)+b0(4)+b1(4); MFMA Q0(a0,b0)           | barrier
//   R1: read a1(8); stage A(t+2)h0+B(t+2)h0; Q1(a0,b1)   | barrier
//   R2: stage B(t+2)h1;                      Q2(a1,b1)   | barrier
//   R3: stage A(t+2)h1;                      Q3(a1,b0); vmcnt | barrier
// MFMA gating: compiler auto-inserts counted lgkmcnt before operand use
// (m97-dump evidence; avoids rule-18 asm-hoist hazards).
// Stage safety (R6/R14 lessons -- barrier-ordered, never timing-ordered):
// every staged region's reads are CONSUMED by an MFMA before the preceding
// barrier (consumed => serviced): Ah0/Bh0 read R0,consumed Q0 -> staged R1;
// Bh1(b1) consumed Q1(R1) -> staged R2; Ah1(a1) consumed Q2(R2) -> staged R3.
// vmcnt ledger == R15 (stages in R1/R2/R3): invariant entering tile t:
// in-flight = [B(t+1)h0,B(t+1)h1,A(t+1)h1](6); R3 vmcnt(6) completes tile
// t+1 + A(t+2)h0. Last pair: hh=0 R3 vmcnt(0) drains. Geometry/swizzle
// (0 conflicts), staging addrs, epilogue: byte-identical to R8/R15.
template <int WRITE_BF16>
__global__ __launch_bounds__(512, 2)
void gemm_bt256(const bfu* __restrict__ A, const bfu* __restrict__ Bm,
                void* __restrict__ Cout, int M, int N, int K) {
  __shared__ __align__(16) bfu Asm[2][256 * 64];  // 32KB per buffer
  __shared__ __align__(16) bfu Bsm[2][256 * 64];
  const int tid = threadIdx.x;
  const int wave = tid >> 6, lane = tid & 63;
  const int lr = lane & 15, kq = lane >> 4;
  const int wm = wave >> 2, wn = wave & 3;  // 2 x 4 wave grid
  const long m0 = (long)blockIdx.y * 256, n0 = (long)blockIdx.x * 256;
  const int NT = K >> 6;  // K-tiles of 64 (even; pairs of 2)

  const int c0j = tid >> 3, c0c = tid & 7;
  const int c1j = (512 + tid) >> 3, c1c = tid & 7;
  const bfu* aSrc0 = A + (m0 + c0j) * (long)K + ((c0c ^ (c0j & 7)) * 8);
  const bfu* aSrc1 = A + (m0 + c1j) * (long)K + ((c1c ^ (c1j & 7)) * 8);
  const bfu* bSrc0 = Bm + (n0 + c0j) * (long)K + ((c0c ^ (c0j & 7)) * 8);
  const bfu* bSrc1 = Bm + (n0 + c1j) * (long)K + ((c1c ^ (c1j & 7)) * 8);

  auto stageA = [&](int t, int buf, int half) {
    long koff = (long)t * 64 + (long)half * 128 * K;
    gload16(aSrc0 + koff, &Asm[buf][half * 8192 + (wave * 64) * 8]);
    gload16(aSrc1 + koff, &Asm[buf][half * 8192 + (512 + wave * 64) * 8]);
  };
  auto stageB = [&](int t, int buf, int half) {
    long koff = (long)t * 64 + (long)half * 128 * K;
    gload16(bSrc0 + koff, &Bsm[buf][half * 8192 + (wave * 64) * 8]);
    gload16(bSrc1 + koff, &Bsm[buf][half * 8192 + (512 + wave * 64) * 8]);
  };
  auto ldsA = [&](int buf, int mf, int ks) -> short8 {
    int row = (mf >> 2) * 128 + wm * 64 + (mf & 3) * 16 + lr;
    int off = (row * 128 + ks * 64 + kq * 16) ^ ((row & 7) << 4);
    return *(const short8*)((const char*)Asm[buf] + off);
  };
  auto ldsB = [&](int buf, int nf, int ks) -> short8 {
    int row = (nf >> 1) * 128 + wn * 32 + (nf & 1) * 16 + lr;
    int off = (row * 128 + ks * 64 + kq * 16) ^ ((row & 7) << 4);
    return *(const short8*)((const char*)Bsm[buf] + off);
  };

  f32x4 acc[8][4] = {};
  short8 a0[4][2], a1[4][2], b0[2][2], b1[2][2];

#define MFMA16(MB, NB, AA, BB)                                                  \
  _Pragma("unroll") for (int mf = 0; mf < 4; ++mf)                              \
      _Pragma("unroll") for (int ks = 0; ks < 2; ++ks)                          \
      _Pragma("unroll") for (int nf = 0; nf < 2; ++nf)                          \
      acc[MB + mf][NB + nf] = __builtin_amdgcn_mfma_f32_16x16x32_bf16(          \
          AA[mf][ks], BB[nf][ks], acc[MB + mf][NB + nf], 0, 0, 0);

  // prologue: stage tiles 0,1 fully (8 half-tiles), leave 3 half-tiles in flight
  stageA(0, 0, 0); stageB(0, 0, 0); stageB(0, 0, 1); stageA(0, 0, 1);
  stageA(1, 1, 0); stageB(1, 1, 0); stageB(1, 1, 1); stageA(1, 1, 1);
  asm volatile("s_waitcnt vmcnt(6)" ::: "memory");
  __builtin_amdgcn_s_barrier();

  for (int tp = 0; tp < NT; tp += 2) {
    const bool more = (tp + 2 < NT);
#pragma unroll
    for (int hh = 0; hh < 2; ++hh) {
      const int bb = hh;          // tile tp+hh lives in buf hh
      const int ts = tp + hh + 2; // tile being staged (same buf, later regions)
      // ---- R0: read a0+b0+b1 (16); MFMA Q0 (b1 serviced under Q0) ----
#pragma unroll
      for (int mf = 0; mf < 4; ++mf) {
        a0[mf][0] = ldsA(bb, mf, 0);
        a0[mf][1] = ldsA(bb, mf, 1);
      }
#pragma unroll
      for (int nf = 0; nf < 2; ++nf) {
        b0[nf][0] = ldsB(bb, nf, 0);
        b0[nf][1] = ldsB(bb, nf, 1);
      }
#pragma unroll
      for (int nf = 0; nf < 2; ++nf) {
        b1[nf][0] = ldsB(bb, 2 + nf, 0);
        b1[nf][1] = ldsB(bb, 2 + nf, 1);
      }
      __builtin_amdgcn_s_setprio(1);
      MFMA16(0, 0, a0, b0)
      __builtin_amdgcn_s_setprio(0);
      __builtin_amdgcn_s_barrier();
      // ---- R1: read a1 (8); stage A(ts)h0+B(ts)h0; MFMA Q1 ----
#pragma unroll
      for (int mf = 0; mf < 4; ++mf) {
        a1[mf][0] = ldsA(bb, 4 + mf, 0);
        a1[mf][1] = ldsA(bb, 4 + mf, 1);
      }
      if (more) { stageA(ts, bb, 0); stageB(ts, bb, 0); }
      __builtin_amdgcn_s_setprio(1);
      MFMA16(0, 2, a0, b1)
      __builtin_amdgcn_s_setprio(0);
      __builtin_amdgcn_s_barrier();
      // ---- R2: stage B(ts)h1; MFMA Q2 ----
      if (more) stageB(ts, bb, 1);
      __builtin_amdgcn_s_setprio(1);
      MFMA16(4, 2, a1, b1)
      __builtin_amdgcn_s_setprio(0);
      __builtin_amdgcn_s_barrier();
      // ---- R3: stage A(ts)h1; MFMA Q3 (b0 held); counted vmcnt ----
      if (more) stageA(ts, bb, 1);
      __builtin_amdgcn_s_setprio(1);
      MFMA16(4, 0, a1, b0)
      __builtin_amdgcn_s_setprio(0);
      if (more) {
        asm volatile("s_waitcnt vmcnt(6)" ::: "memory");
      } else if (hh == 0) {
        asm volatile("s_waitcnt vmcnt(0)" ::: "memory");  // last pair: drain
      }
      __builtin_amdgcn_s_barrier();
    }
  }
#undef MFMA16

  // epilogue: C/D layout col=lane&15, row=(lane>>4)*4+reg; fragment->global
  // mapping mirrors ldsA/ldsB row formulas (half-straddling wave grid).
#pragma unroll
  for (int mf = 0; mf < 8; ++mf)
#pragma unroll
    for (int nf = 0; nf < 4; ++nf)
#pragma unroll
      for (int r = 0; r < 4; ++r) {
        long row = m0 + (mf >> 2) * 128 + wm * 64 + (mf & 3) * 16 + kq * 4 + r;
        long col = n0 + (nf >> 1) * 128 + wn * 32 + (nf & 1) * 16 + lr;
        float v = acc[mf][nf][r];
        if (WRITE_BF16)
          ((bfu*)Cout)[row * N + col] = f2b(v);
        else
          ((float*)Cout)[row * N + col] = v;
      }
}

// ---------------- GEMM: 128^2 m97-style (batched K/V projection) --------------
template <int WRITE_BF16>
__global__ __launch_bounds__(256, 2)
void gemm_bt(const bfu* __restrict__ A, const bfu* __restrict__ Bm,
             void* __restrict__ Cout, int M, int N, int K) {
  __shared__ __align__(16) bfu As[128 * 32];
  __shared__ __align__(16) bfu Bs[128 * 32];
  const int tid = threadIdx.x;
  const int wave = tid >> 6, lane = tid & 63;
  const int lr = lane & 15, kq = lane >> 4;
  const int wm = wave >> 1, wn = wave & 1;
  const long m0 = (long)blockIdx.y * 128, n0 = (long)blockIdx.x * 128;

  f32x4 acc[4][4] = {};

  for (int kk = 0; kk < K; kk += 32) {
#pragma unroll
    for (int i = 0; i < 2; ++i) {
      int tt = i * 256 + tid;
      long row = tt >> 2;
      int col = (tt & 3) * 8;
      gload16(A + (m0 + row) * K + kk + col, &As[(i * 256 + wave * 64) * 8]);
      gload16(Bm + (n0 + row) * K + kk + col, &Bs[(i * 256 + wave * 64) * 8]);
    }
    __syncthreads();
    short8 a[4], b[4];
#pragma unroll
    for (int mt = 0; mt < 4; ++mt)
      a[mt] = *(const short8*)&As[(wm * 64 + mt * 16 + lr) * 32 + kq * 8];
#pragma unroll
    for (int nt = 0; nt < 4; ++nt)
      b[nt] = *(const short8*)&Bs[(wn * 64 + nt * 16 + lr) * 32 + kq * 8];
#pragma unroll
    for (int mt = 0; mt < 4; ++mt)
#pragma unroll
      for (int nt = 0; nt < 4; ++nt)
        acc[mt][nt] = __builtin_amdgcn_mfma_f32_16x16x32_bf16(
            a[mt], b[nt], acc[mt][nt], 0, 0, 0);
    __syncthreads();
  }
#pragma unroll
  for (int mt = 0; mt < 4; ++mt)
#pragma unroll
    for (int nt = 0; nt < 4; ++nt)
#pragma unroll
      for (int r = 0; r < 4; ++r) {
        long row = m0 + wm * 64 + mt * 16 + kq * 4 + r;
        long col = n0 + wn * 64 + nt * 16 + lr;
        float v = acc[mt][nt][r];
        if (WRITE_BF16)
          ((bfu*)Cout)[row * N + col] = f2b(v);
        else
          ((float*)Cout)[row * N + col] = v;
      }
}

// ------ V transpose: KVb[B*NQ][8192] (V = cols 4096..8191) -> Vt[B*H][HD][NQ] --
__global__ void transpose_v(const bfu* __restrict__ KVb, bfu* __restrict__ Vt) {
  __shared__ bfu t[32][33];
  const int bh = blockIdx.z;
  const int tq = blockIdx.x;
  const int td = blockIdx.y;
  const int b = bh >> 5, h = bh & 31;
  const int tx = threadIdx.x & 31, ty = threadIdx.x >> 5;
  const bfu* src =
      KVb + ((long)(b * NQn + tq * 32)) * 8192 + 4096 + h * HDn + td * 32;
#pragma unroll
  for (int i = 0; i < 32; i += 8) t[ty + i][tx] = src[(long)(ty + i) * 8192 + tx];
  __syncthreads();
  bfu* dst = Vt + ((long)bh * HDn + td * 32) * NQn + tq * 32;
#pragma unroll
  for (int i = 0; i < 32; i += 8) dst[(long)(ty + i) * NQn + tx] = t[tx][ty + i];
}

// ========== fused attention (R9/R11-verified flash-style, K from KVb) =========
__global__ __launch_bounds__(256, 4)
void attn_kernel(const bfu* __restrict__ Qb, const bfu* __restrict__ KVb,
                 const bfu* __restrict__ Vt, const float* __restrict__ mask,
                 bfu* __restrict__ AO) {
  __shared__ __align__(16) bfu Ks[2][4096];  // 2 x 8KB: [32 keys][128 d] swz
  __shared__ __align__(16) bfu Vs[2][4096];  // 2 x 8KB: [128 d][32 keys] lin
  const int bid = blockIdx.x;                // natural order (R2: no XCD swz)
  const int h = bid & (Hn - 1);
  const int b = (bid >> 5) & (Bn - 1);
  const int qt0 = bid >> 6;                  // [0,64)
  const long q0 = (long)qt0 * 64;
  const int tid = threadIdx.x;
  const int wave = tid >> 6, lane = tid & 63;
  const int lr = lane & 15, kq = lane >> 4;
  const float scale = 0.08838834764831845f;  // 1/sqrt(128)

  const long qrow = (long)b * Sn + q0 + wave * 16 + lr;
  const bfu* Kblk = KVb + (long)b * NQn * 8192 + h * HDn;  // K: stride 8192
  const bfu* Vblk = Vt + ((long)(b * Hn + h)) * HDn * NQn;
  const float* mrow = mask + ((long)b * Sn + q0 + wave * 16 + lr) * NQn;

  auto stageK = [&](int kt, int buf) {
#pragma unroll
    for (int i = 0; i < 2; ++i) {
      int c = i * 256 + tid;
      int j = c >> 4, c16 = c & 15;
      gload16(Kblk + (long)(kt * 32 + j) * 8192 + ((c16 ^ (j & 7)) * 8),
              &Ks[buf][(i * 256 + wave * 64) * 8]);
    }
  };
  auto stageV = [&](int kt, int buf) {
#pragma unroll
    for (int i = 0; i < 2; ++i) {
      int c = i * 256 + tid;
      int j = c >> 2, c4 = c & 3;
      gload16(Vblk + (long)j * NQn + kt * 32 + c4 * 8,
              &Vs[buf][(i * 256 + wave * 64) * 8]);
    }
  };

  stageK(0, 0);
  stageV(0, 0);

  const bfu* Qbase = Qb + qrow * HIDn + h * HDn;
  short8 qf[4];
#pragma unroll
  for (int ks = 0; ks < 4; ++ks)
    qf[ks] = *(const short8*)&Qbase[ks * 32 + kq * 8];

  f32x4 o[8] = {};
  float rsum = 0.f;

  for (int kt = 0; kt < 18; ++kt) {
    __syncthreads();
    const int buf = kt & 1;
    if (kt < 17) {
      stageK(kt + 1, buf ^ 1);
      stageV(kt + 1, buf ^ 1);
    }
    const char* kb = (const char*)Ks[buf];
    f32x4 s0 = {}, s1 = {};
#pragma unroll
    for (int ks = 0; ks < 4; ++ks) {
      short8 kf0 = *(const short8*)(kb + ((lr * 256 + ks * 64 + kq * 16) ^
                                          ((lr & 7) << 4)));
      short8 kf1 = *(const short8*)(kb + (((16 + lr) * 256 + ks * 64 + kq * 16) ^
                                          ((lr & 7) << 4)));
      s0 = __builtin_amdgcn_mfma_f32_16x16x32_bf16(kf0, qf[ks], s0, 0, 0, 0);
      s1 = __builtin_amdgcn_mfma_f32_16x16x32_bf16(kf1, qf[ks], s1, 0, 0, 0);
    }
    float4 m0 = *(const float4*)&mrow[kt * 32 + kq * 4];
    float4 m1 = *(const float4*)&mrow[kt * 32 + 16 + kq * 4];
    float p00 = __expf(s0[0] * scale + m0.x), p01 = __expf(s0[1] * scale + m0.y);
    float p02 = __expf(s0[2] * scale + m0.z), p03 = __expf(s0[3] * scale + m0.w);
    float p10 = __expf(s1[0] * scale + m1.x), p11 = __expf(s1[1] * scale + m1.y);
    float p12 = __expf(s1[2] * scale + m1.z), p13 = __expf(s1[3] * scale + m1.w);
    rsum += ((p00 + p01) + (p02 + p03)) + ((p10 + p11) + (p12 + p13));
    int pk0_0 = (int)((uint32_t)f2b(p00) | ((uint32_t)f2b(p01) << 16));
    int pk0_1 = (int)((uint32_t)f2b(p02) | ((uint32_t)f2b(p03) << 16));
    int pk1_0 = (int)((uint32_t)f2b(p10) | ((uint32_t)f2b(p11) << 16));
    int pk1_1 = (int)((uint32_t)f2b(p12) | ((uint32_t)f2b(p13) << 16));
    const int sLo = lr + (((kq & 1) << 1) << 4);
    const int sHi = sLo + 16;
    int b0, b1, b2, b3;
    {
      int v0 = __shfl(pk0_0, sLo, 64), v1 = __shfl(pk1_0, sLo, 64);
      b0 = (kq < 2) ? v0 : v1;
      v0 = __shfl(pk0_1, sLo, 64); v1 = __shfl(pk1_1, sLo, 64);
      b1 = (kq < 2) ? v0 : v1;
      v0 = __shfl(pk0_0, sHi, 64); v1 = __shfl(pk1_0, sHi, 64);
      b2 = (kq < 2) ? v0 : v1;
      v0 = __shfl(pk0_1, sHi, 64); v1 = __shfl(pk1_1, sHi, 64);
      b3 = (kq < 2) ? v0 : v1;
    }
    int4 pfi = {b0, b1, b2, b3};
    short8 pfrag = __builtin_bit_cast(short8, pfi);
    const char* vb = (const char*)Vs[buf];
#pragma unroll
    for (int dt = 0; dt < 8; ++dt) {
      short8 vf = *(const short8*)(vb + ((dt * 16 + lr) * 64 + kq * 16));
      o[dt] = __builtin_amdgcn_mfma_f32_16x16x32_bf16(vf, pfrag, o[dt], 0, 0, 0);
    }
  }

  rsum += __shfl_xor(rsum, 16, 64);
  rsum += __shfl_xor(rsum, 32, 64);
  const float inv = 1.0f / rsum;

  bfu* Obase = AO + qrow * HIDn + h * HDn;
#pragma unroll
  for (int dt = 0; dt < 8; ++dt) {
    uint64_t pk = (uint64_t)f2b(o[dt][0] * inv) |
                  ((uint64_t)f2b(o[dt][1] * inv) << 16) |
                  ((uint64_t)f2b(o[dt][2] * inv) << 32) |
                  ((uint64_t)f2b(o[dt][3] * inv) << 48);
    *(uint64_t*)&Obase[dt * 16 + kq * 4] = pk;
  }
}

// ------------------------------- launcher --------------------------------------
extern "C" void kernel_launch(void* const* d_in, const int* in_sizes, int n_in,
                              void* d_out, int out_size, void* d_ws, size_t ws_size,
                              hipStream_t stream) {
  const float* hs = (const float*)d_in[0];
  const float* bp = (const float*)d_in[1];
  const float* mask = (const float*)d_in[2];
  const float* Wq = (const float*)d_in[3];
  const float* Wk = (const float*)d_in[4];
  const float* Wv = (const float*)d_in[5];
  const float* Wo = (const float*)d_in[6];
  float* out = (float*)d_out;

  const long M1 = (long)Bn * Sn;   // 8192
  const long M2 = (long)Bn * NQn;  // 1152
  char* ws = (char*)d_ws;
  bfu* hb = (bfu*)(ws + 0);                  // 67,108,864  (also AO)
  bfu* bb = (bfu*)(ws + 67108864);           //  9,437,184
  bfu* w1 = (bfu*)(ws + 76546048);           // 33,554,432  (Wq, later Wo)
  bfu* wkv = (bfu*)(ws + 110100480);         // 67,108,864  (Wk rows 0-4095,
                                             //              Wv rows 4096-8191)
  bfu* Qb = (bfu*)(ws + 177209344);          // 67,108,864
  bfu* KVb = (bfu*)(ws + 244318208);         // 18,874,368  [1152][8192]
  bfu* Vt = (bfu*)(ws + 263192576);          //  9,437,184  -> total 272,629,760

  // fused front casts: hs, bp, Wq, Wk, Wv (all n8 divisible by 256)
  const int n8_hs = (int)(M1 * HIDn / 8);          // 4,194,304
  const int n8_bp = (int)(M2 * HIDn / 8);          //   589,824
  const int n8_w = (int)((long)HIDn * HIDn / 8);   // 2,097,152
  const long tot8 = (long)n8_hs + n8_bp + 3L * n8_w;
  cast5<<<dim3((int)(tot8 / 256)), dim3(256), 0, stream>>>(
      hs, hb, n8_hs, bp, bb, n8_bp, Wq, w1, n8_w, Wk, wkv, n8_w, Wv,
      wkv + (long)HIDn * HIDn, n8_w);

  gemm_bt256<1><<<dim3(HIDn / 256, M1 / 256), dim3(512), 0, stream>>>(
      hb, w1, Qb, (int)M1, HIDn, HIDn);
  // batched K+V projection: C[1152][8192] = bb @ [Wk;Wv]^T  (one dispatch)
  gemm_bt<1><<<dim3(8192 / 128, M2 / 128), dim3(256), 0, stream>>>(
      bb, wkv, KVb, (int)M2, 8192, HIDn);

  cast_f32_bf16<<<dim3(n8_w / 256), dim3(256), 0, stream>>>(
      Wo, w1, n8_w);  // w1 slot free after Q-proj
  transpose_v<<<dim3(NQn / 32, HDn / 32, Bn * Hn), dim3(256), 0, stream>>>(
      KVb, Vt);

  attn_kernel<<<dim3((Sn / 64) * Bn * Hn), dim3(256), 0, stream>>>(
      Qb, KVb, Vt, mask, hb /*AO aliases hb*/);

  gemm_bt256<0><<<dim3(HIDn / 256, M1 / 256), dim3(512), 0, stream>>>(
      hb, w1, out, (int)M1, HIDn, HIDn);
}

// Round 17
// 889.521 us; speedup vs baseline: 1.3379x; 1.3379x over previous
//
#include <hip/hip_runtime.h>
#include <stdint.h>

// Problem constants
#define Bn   2
#define Sn   4096
#define NQn  576
#define Hn   32
#define HDn  128
#define HIDn 4096

typedef unsigned short bfu;  // raw bf16 bits
typedef short short8 __attribute__((ext_vector_type(8)));
typedef float f32x4 __attribute__((ext_vector_type(4)));

__device__ __forceinline__ bfu f2b(float f) {
  uint32_t x = __builtin_bit_cast(uint32_t, f);
  return (bfu)((x + 0x7fffu + ((x >> 16) & 1u)) >> 16);  // RNE
}

__device__ __forceinline__ void gload16(const void* g, void* l) {
  // async global->LDS, 16B per lane; LDS dest = wave-uniform base + lane*16
  __builtin_amdgcn_global_load_lds(
      (const __attribute__((address_space(1))) uint32_t*)g,
      (__attribute__((address_space(3))) uint32_t*)l, 16, 0, 0);
}

__device__ __forceinline__ void cast8(const float* s, bfu* d, long i) {
  const float4* in4 = (const float4*)s;
  float4 a = in4[2 * i], c = in4[2 * i + 1];
  short8 v;
  v[0] = (short)f2b(a.x); v[1] = (short)f2b(a.y);
  v[2] = (short)f2b(a.z); v[3] = (short)f2b(a.w);
  v[4] = (short)f2b(c.x); v[5] = (short)f2b(c.y);
  v[6] = (short)f2b(c.z); v[7] = (short)f2b(c.w);
  ((short8*)d)[i] = v;
}

// ---------------- cast f32 -> bf16 (single input) ------------------------------
__global__ void cast_f32_bf16(const float* __restrict__ in, bfu* __restrict__ out,
                              int n8) {
  long i = (long)blockIdx.x * 256 + threadIdx.x;
  if (i >= n8) return;
  cast8(in, out, i);
}

// ---------------- fused 5-input cast (one launch; all n8 divide 256) -----------
__global__ void cast5(const float* s0, bfu* d0, int n0, const float* s1, bfu* d1,
                      int n1, const float* s2, bfu* d2, int n2, const float* s3,
                      bfu* d3, int n3, const float* s4, bfu* d4, int n4) {
  long gid = (long)blockIdx.x * 256 + threadIdx.x;
  if (gid < n0) { cast8(s0, d0, gid); return; }
  gid -= n0;
  if (gid < n1) { cast8(s1, d1, gid); return; }
  gid -= n1;
  if (gid < n2) { cast8(s2, d2, gid); return; }
  gid -= n2;
  if (gid < n3) { cast8(s3, d3, gid); return; }
  gid -= n3;
  if (gid < n4) cast8(s4, d4, gid);
}

// ======== 256^2 GEMM, m201 8-phase port (R15-verified BEST): C = A @ Bm^T =====
// R16 post-mortem: merging read-regions into MFMA regions (4 barriers,
// no lgkmcnt gate) REGRESSED 287->450us, MfmaUtil 41.5->25: setprio'd MFMA
// clusters stalled mid-cluster on in-order LDS servicing (first MFMA needs
// the 12th-issued read), defeating phase alignment. R15's explicit-gated
// 8-phase is the measured optimum of 7 structures tried (37.7/39.9/25/34/
// null/41.5/25). Restored byte-exact:
//   Q0: reads a0(8)+b0(4), NO stage, lgkmcnt(8) | bar | lgkmcnt(0) | MFMA Q0
//   Q1: reads b1(4); stage A(t+2)h0+B(t+2)h0    | bar | lgkmcnt(0) | MFMA Q1
//   Q2: reads a1(8); stage B(t+2)h1             | bar | lgkmcnt(0) | MFMA Q2
//   Q3: no reads (b0 held); stage A(t+2)h1; MFMA Q3; vmcnt(6) | bar
// Stage safety barrier-ordered (region staged one phase after last read).
// vmcnt ledger: in-flight entering tile t = [B(t+1)h0,B(t+1)h1,A(t+1)h1];
// Q3 vmcnt(6) completes tile t+1 + A(t+2)h0; last pair drains vmcnt(0).
// Geometry/swizzle (0 conflicts), staging addrs, epilogue: R8-exact.
template <int WRITE_BF16>
__global__ __launch_bounds__(512, 2)
void gemm_bt256(const bfu* __restrict__ A, const bfu* __restrict__ Bm,
                void* __restrict__ Cout, int M, int N, int K) {
  __shared__ __align__(16) bfu Asm[2][256 * 64];  // 32KB per buffer
  __shared__ __align__(16) bfu Bsm[2][256 * 64];
  const int tid = threadIdx.x;
  const int wave = tid >> 6, lane = tid & 63;
  const int lr = lane & 15, kq = lane >> 4;
  const int wm = wave >> 2, wn = wave & 3;  // 2 x 4 wave grid
  const long m0 = (long)blockIdx.y * 256, n0 = (long)blockIdx.x * 256;
  const int NT = K >> 6;  // K-tiles of 64 (even; pairs of 2)

  const int c0j = tid >> 3, c0c = tid & 7;
  const int c1j = (512 + tid) >> 3, c1c = tid & 7;
  const bfu* aSrc0 = A + (m0 + c0j) * (long)K + ((c0c ^ (c0j & 7)) * 8);
  const bfu* aSrc1 = A + (m0 + c1j) * (long)K + ((c1c ^ (c1j & 7)) * 8);
  const bfu* bSrc0 = Bm + (n0 + c0j) * (long)K + ((c0c ^ (c0j & 7)) * 8);
  const bfu* bSrc1 = Bm + (n0 + c1j) * (long)K + ((c1c ^ (c1j & 7)) * 8);

  auto stageA = [&](int t, int buf, int half) {
    long koff = (long)t * 64 + (long)half * 128 * K;
    gload16(aSrc0 + koff, &Asm[buf][half * 8192 + (wave * 64) * 8]);
    gload16(aSrc1 + koff, &Asm[buf][half * 8192 + (512 + wave * 64) * 8]);
  };
  auto stageB = [&](int t, int buf, int half) {
    long koff = (long)t * 64 + (long)half * 128 * K;
    gload16(bSrc0 + koff, &Bsm[buf][half * 8192 + (wave * 64) * 8]);
    gload16(bSrc1 + koff, &Bsm[buf][half * 8192 + (512 + wave * 64) * 8]);
  };
  auto ldsA = [&](int buf, int mf, int ks) -> short8 {
    int row = (mf >> 2) * 128 + wm * 64 + (mf & 3) * 16 + lr;
    int off = (row * 128 + ks * 64 + kq * 16) ^ ((row & 7) << 4);
    return *(const short8*)((const char*)Asm[buf] + off);
  };
  auto ldsB = [&](int buf, int nf, int ks) -> short8 {
    int row = (nf >> 1) * 128 + wn * 32 + (nf & 1) * 16 + lr;
    int off = (row * 128 + ks * 64 + kq * 16) ^ ((row & 7) << 4);
    return *(const short8*)((const char*)Bsm[buf] + off);
  };

  f32x4 acc[8][4] = {};
  short8 a0[4][2], a1[4][2], b0[2][2], b1[2][2];

#define MFMA16(MB, NB, AA, BB)                                                  \
  _Pragma("unroll") for (int mf = 0; mf < 4; ++mf)                              \
      _Pragma("unroll") for (int ks = 0; ks < 2; ++ks)                          \
      _Pragma("unroll") for (int nf = 0; nf < 2; ++nf)                          \
      acc[MB + mf][NB + nf] = __builtin_amdgcn_mfma_f32_16x16x32_bf16(          \
          AA[mf][ks], BB[nf][ks], acc[MB + mf][NB + nf], 0, 0, 0);

  // prologue: stage tiles 0,1 fully (8 half-tiles), leave 3 half-tiles in flight
  stageA(0, 0, 0); stageB(0, 0, 0); stageB(0, 0, 1); stageA(0, 0, 1);
  stageA(1, 1, 0); stageB(1, 1, 0); stageB(1, 1, 1); stageA(1, 1, 1);
  asm volatile("s_waitcnt vmcnt(6)" ::: "memory");
  __builtin_amdgcn_s_barrier();

  for (int tp = 0; tp < NT; tp += 2) {
    const bool more = (tp + 2 < NT);
#pragma unroll
    for (int hh = 0; hh < 2; ++hh) {
      const int bb = hh;          // tile tp+hh lives in buf hh
      const int ts = tp + hh + 2; // tile being staged (same buf, later phases)
      // ---- phase Q0: read a0(8)+b0(4); NO stage; lgkmcnt(8) ----
#pragma unroll
      for (int mf = 0; mf < 4; ++mf) {
        a0[mf][0] = ldsA(bb, mf, 0);
        a0[mf][1] = ldsA(bb, mf, 1);
      }
#pragma unroll
      for (int nf = 0; nf < 2; ++nf) {
        b0[nf][0] = ldsB(bb, nf, 0);
        b0[nf][1] = ldsB(bb, nf, 1);
      }
      asm volatile("s_waitcnt lgkmcnt(8)" ::: "memory");
      __builtin_amdgcn_s_barrier();
      asm volatile("s_waitcnt lgkmcnt(0)" ::: "memory");
      __builtin_amdgcn_s_setprio(1);
      MFMA16(0, 0, a0, b0)
      __builtin_amdgcn_s_setprio(0);
      __builtin_amdgcn_s_barrier();
      // ---- phase Q1: read b1(4); stage A(ts)h0 + B(ts)h0 ----
#pragma unroll
      for (int nf = 0; nf < 2; ++nf) {
        b1[nf][0] = ldsB(bb, 2 + nf, 0);
        b1[nf][1] = ldsB(bb, 2 + nf, 1);
      }
      if (more) { stageA(ts, bb, 0); stageB(ts, bb, 0); }
      __builtin_amdgcn_s_barrier();
      asm volatile("s_waitcnt lgkmcnt(0)" ::: "memory");
      __builtin_amdgcn_s_setprio(1);
      MFMA16(0, 2, a0, b1)
      __builtin_amdgcn_s_setprio(0);
      __builtin_amdgcn_s_barrier();
      // ---- phase Q2: read a1(8); stage B(ts)h1 ----
#pragma unroll
      for (int mf = 0; mf < 4; ++mf) {
        a1[mf][0] = ldsA(bb, 4 + mf, 0);
        a1[mf][1] = ldsA(bb, 4 + mf, 1);
      }
      if (more) stageB(ts, bb, 1);
      __builtin_amdgcn_s_barrier();
      asm volatile("s_waitcnt lgkmcnt(0)" ::: "memory");
      __builtin_amdgcn_s_setprio(1);
      MFMA16(4, 2, a1, b1)
      __builtin_amdgcn_s_setprio(0);
      __builtin_amdgcn_s_barrier();
      // ---- phase Q3: no reads (b0 held); stage A(ts)h1; counted vmcnt ----
      if (more) stageA(ts, bb, 1);
      __builtin_amdgcn_s_barrier();
      __builtin_amdgcn_s_setprio(1);
      MFMA16(4, 0, a1, b0)
      __builtin_amdgcn_s_setprio(0);
      if (more) {
        asm volatile("s_waitcnt vmcnt(6)" ::: "memory");
      } else if (hh == 0) {
        asm volatile("s_waitcnt vmcnt(0)" ::: "memory");  // last pair: drain
      }
      __builtin_amdgcn_s_barrier();
    }
  }
#undef MFMA16

  // epilogue: C/D layout col=lane&15, row=(lane>>4)*4+reg; fragment->global
  // mapping mirrors ldsA/ldsB row formulas (half-straddling wave grid).
#pragma unroll
  for (int mf = 0; mf < 8; ++mf)
#pragma unroll
    for (int nf = 0; nf < 4; ++nf)
#pragma unroll
      for (int r = 0; r < 4; ++r) {
        long row = m0 + (mf >> 2) * 128 + wm * 64 + (mf & 3) * 16 + kq * 4 + r;
        long col = n0 + (nf >> 1) * 128 + wn * 32 + (nf & 1) * 16 + lr;
        float v = acc[mf][nf][r];
        if (WRITE_BF16)
          ((bfu*)Cout)[row * N + col] = f2b(v);
        else
          ((float*)Cout)[row * N + col] = v;
      }
}

// ---------------- GEMM: 128^2 m97-style (batched K/V projection) --------------
template <int WRITE_BF16>
__global__ __launch_bounds__(256, 2)
void gemm_bt(const bfu* __restrict__ A, const bfu* __restrict__ Bm,
             void* __restrict__ Cout, int M, int N, int K) {
  __shared__ __align__(16) bfu As[128 * 32];
  __shared__ __align__(16) bfu Bs[128 * 32];
  const int tid = threadIdx.x;
  const int wave = tid >> 6, lane = tid & 63;
  const int lr = lane & 15, kq = lane >> 4;
  const int wm = wave >> 1, wn = wave & 1;
  const long m0 = (long)blockIdx.y * 128, n0 = (long)blockIdx.x * 128;

  f32x4 acc[4][4] = {};

  for (int kk = 0; kk < K; kk += 32) {
#pragma unroll
    for (int i = 0; i < 2; ++i) {
      int tt = i * 256 + tid;
      long row = tt >> 2;
      int col = (tt & 3) * 8;
      gload16(A + (m0 + row) * K + kk + col, &As[(i * 256 + wave * 64) * 8]);
      gload16(Bm + (n0 + row) * K + kk + col, &Bs[(i * 256 + wave * 64) * 8]);
    }
    __syncthreads();
    short8 a[4], b[4];
#pragma unroll
    for (int mt = 0; mt < 4; ++mt)
      a[mt] = *(const short8*)&As[(wm * 64 + mt * 16 + lr) * 32 + kq * 8];
#pragma unroll
    for (int nt = 0; nt < 4; ++nt)
      b[nt] = *(const short8*)&Bs[(wn * 64 + nt * 16 + lr) * 32 + kq * 8];
#pragma unroll
    for (int mt = 0; mt < 4; ++mt)
#pragma unroll
      for (int nt = 0; nt < 4; ++nt)
        acc[mt][nt] = __builtin_amdgcn_mfma_f32_16x16x32_bf16(
            a[mt], b[nt], acc[mt][nt], 0, 0, 0);
    __syncthreads();
  }
#pragma unroll
  for (int mt = 0; mt < 4; ++mt)
#pragma unroll
    for (int nt = 0; nt < 4; ++nt)
#pragma unroll
      for (int r = 0; r < 4; ++r) {
        long row = m0 + wm * 64 + mt * 16 + kq * 4 + r;
        long col = n0 + wn * 64 + nt * 16 + lr;
        float v = acc[mt][nt][r];
        if (WRITE_BF16)
          ((bfu*)Cout)[row * N + col] = f2b(v);
        else
          ((float*)Cout)[row * N + col] = v;
      }
}

// ------ V transpose: KVb[B*NQ][8192] (V = cols 4096..8191) -> Vt[B*H][HD][NQ] --
__global__ void transpose_v(const bfu* __restrict__ KVb, bfu* __restrict__ Vt) {
  __shared__ bfu t[32][33];
  const int bh = blockIdx.z;
  const int tq = blockIdx.x;
  const int td = blockIdx.y;
  const int b = bh >> 5, h = bh & 31;
  const int tx = threadIdx.x & 31, ty = threadIdx.x >> 5;
  const bfu* src =
      KVb + ((long)(b * NQn + tq * 32)) * 8192 + 4096 + h * HDn + td * 32;
#pragma unroll
  for (int i = 0; i < 32; i += 8) t[ty + i][tx] = src[(long)(ty + i) * 8192 + tx];
  __syncthreads();
  bfu* dst = Vt + ((long)bh * HDn + td * 32) * NQn + tq * 32;
#pragma unroll
  for (int i = 0; i < 32; i += 8) dst[(long)(ty + i) * NQn + tx] = t[tx][ty + i];
}

// ========== fused attention (R9/R11-verified flash-style, K from KVb) =========
__global__ __launch_bounds__(256, 4)
void attn_kernel(const bfu* __restrict__ Qb, const bfu* __restrict__ KVb,
                 const bfu* __restrict__ Vt, const float* __restrict__ mask,
                 bfu* __restrict__ AO) {
  __shared__ __align__(16) bfu Ks[2][4096];  // 2 x 8KB: [32 keys][128 d] swz
  __shared__ __align__(16) bfu Vs[2][4096];  // 2 x 8KB: [128 d][32 keys] lin
  const int bid = blockIdx.x;                // natural order (R2: no XCD swz)
  const int h = bid & (Hn - 1);
  const int b = (bid >> 5) & (Bn - 1);
  const int qt0 = bid >> 6;                  // [0,64)
  const long q0 = (long)qt0 * 64;
  const int tid = threadIdx.x;
  const int wave = tid >> 6, lane = tid & 63;
  const int lr = lane & 15, kq = lane >> 4;
  const float scale = 0.08838834764831845f;  // 1/sqrt(128)

  const long qrow = (long)b * Sn + q0 + wave * 16 + lr;
  const bfu* Kblk = KVb + (long)b * NQn * 8192 + h * HDn;  // K: stride 8192
  const bfu* Vblk = Vt + ((long)(b * Hn + h)) * HDn * NQn;
  const float* mrow = mask + ((long)b * Sn + q0 + wave * 16 + lr) * NQn;

  auto stageK = [&](int kt, int buf) {
#pragma unroll
    for (int i = 0; i < 2; ++i) {
      int c = i * 256 + tid;
      int j = c >> 4, c16 = c & 15;
      gload16(Kblk + (long)(kt * 32 + j) * 8192 + ((c16 ^ (j & 7)) * 8),
              &Ks[buf][(i * 256 + wave * 64) * 8]);
    }
  };
  auto stageV = [&](int kt, int buf) {
#pragma unroll
    for (int i = 0; i < 2; ++i) {
      int c = i * 256 + tid;
      int j = c >> 2, c4 = c & 3;
      gload16(Vblk + (long)j * NQn + kt * 32 + c4 * 8,
              &Vs[buf][(i * 256 + wave * 64) * 8]);
    }
  };

  stageK(0, 0);
  stageV(0, 0);

  const bfu* Qbase = Qb + qrow * HIDn + h * HDn;
  short8 qf[4];
#pragma unroll
  for (int ks = 0; ks < 4; ++ks)
    qf[ks] = *(const short8*)&Qbase[ks * 32 + kq * 8];

  f32x4 o[8] = {};
  float rsum = 0.f;

  for (int kt = 0; kt < 18; ++kt) {
    __syncthreads();
    const int buf = kt & 1;
    if (kt < 17) {
      stageK(kt + 1, buf ^ 1);
      stageV(kt + 1, buf ^ 1);
    }
    const char* kb = (const char*)Ks[buf];
    f32x4 s0 = {}, s1 = {};
#pragma unroll
    for (int ks = 0; ks < 4; ++ks) {
      short8 kf0 = *(const short8*)(kb + ((lr * 256 + ks * 64 + kq * 16) ^
                                          ((lr & 7) << 4)));
      short8 kf1 = *(const short8*)(kb + (((16 + lr) * 256 + ks * 64 + kq * 16) ^
                                          ((lr & 7) << 4)));
      s0 = __builtin_amdgcn_mfma_f32_16x16x32_bf16(kf0, qf[ks], s0, 0, 0, 0);
      s1 = __builtin_amdgcn_mfma_f32_16x16x32_bf16(kf1, qf[ks], s1, 0, 0, 0);
    }
    float4 m0 = *(const float4*)&mrow[kt * 32 + kq * 4];
    float4 m1 = *(const float4*)&mrow[kt * 32 + 16 + kq * 4];
    float p00 = __expf(s0[0] * scale + m0.x), p01 = __expf(s0[1] * scale + m0.y);
    float p02 = __expf(s0[2] * scale + m0.z), p03 = __expf(s0[3] * scale + m0.w);
    float p10 = __expf(s1[0] * scale + m1.x), p11 = __expf(s1[1] * scale + m1.y);
    float p12 = __expf(s1[2] * scale + m1.z), p13 = __expf(s1[3] * scale + m1.w);
    rsum += ((p00 + p01) + (p02 + p03)) + ((p10 + p11) + (p12 + p13));
    int pk0_0 = (int)((uint32_t)f2b(p00) | ((uint32_t)f2b(p01) << 16));
    int pk0_1 = (int)((uint32_t)f2b(p02) | ((uint32_t)f2b(p03) << 16));
    int pk1_0 = (int)((uint32_t)f2b(p10) | ((uint32_t)f2b(p11) << 16));
    int pk1_1 = (int)((uint32_t)f2b(p12) | ((uint32_t)f2b(p13) << 16));
    const int sLo = lr + (((kq & 1) << 1) << 4);
    const int sHi = sLo + 16;
    int b0, b1, b2, b3;
    {
      int v0 = __shfl(pk0_0, sLo, 64), v1 = __shfl(pk1_0, sLo, 64);
      b0 = (kq < 2) ? v0 : v1;
      v0 = __shfl(pk0_1, sLo, 64); v1 = __shfl(pk1_1, sLo, 64);
      b1 = (kq < 2) ? v0 : v1;
      v0 = __shfl(pk0_0, sHi, 64); v1 = __shfl(pk1_0, sHi, 64);
      b2 = (kq < 2) ? v0 : v1;
      v0 = __shfl(pk0_1, sHi, 64); v1 = __shfl(pk1_1, sHi, 64);
      b3 = (kq < 2) ? v0 : v1;
    }
    int4 pfi = {b0, b1, b2, b3};
    short8 pfrag = __builtin_bit_cast(short8, pfi);
    const char* vb = (const char*)Vs[buf];
#pragma unroll
    for (int dt = 0; dt < 8; ++dt) {
      short8 vf = *(const short8*)(vb + ((dt * 16 + lr) * 64 + kq * 16));
      o[dt] = __builtin_amdgcn_mfma_f32_16x16x32_bf16(vf, pfrag, o[dt], 0, 0, 0);
    }
  }

  rsum += __shfl_xor(rsum, 16, 64);
  rsum += __shfl_xor(rsum, 32, 64);
  const float inv = 1.0f / rsum;

  bfu* Obase = AO + qrow * HIDn + h * HDn;
#pragma unroll
  for (int dt = 0; dt < 8; ++dt) {
    uint64_t pk = (uint64_t)f2b(o[dt][0] * inv) |
                  ((uint64_t)f2b(o[dt][1] * inv) << 16) |
                  ((uint64_t)f2b(o[dt][2] * inv) << 32) |
                  ((uint64_t)f2b(o[dt][3] * inv) << 48);
    *(uint64_t*)&Obase[dt * 16 + kq * 4] = pk;
  }
}

// ------------------------------- launcher --------------------------------------
extern "C" void kernel_launch(void* const* d_in, const int* in_sizes, int n_in,
                              void* d_out, int out_size, void* d_ws, size_t ws_size,
                              hipStream_t stream) {
  const float* hs = (const float*)d_in[0];
  const float* bp = (const float*)d_in[1];
  const float* mask = (const float*)d_in[2];
  const float* Wq = (const float*)d_in[3];
  const float* Wk = (const float*)d_in[4];
  const float* Wv = (const float*)d_in[5];
  const float* Wo = (const float*)d_in[6];
  float* out = (float*)d_out;

  const long M1 = (long)Bn * Sn;   // 8192
  const long M2 = (long)Bn * NQn;  // 1152
  char* ws = (char*)d_ws;
  bfu* hb = (bfu*)(ws + 0);                  // 67,108,864  (also AO)
  bfu* bb = (bfu*)(ws + 67108864);           //  9,437,184
  bfu* w1 = (bfu*)(ws + 76546048);           // 33,554,432  (Wq, later Wo)
  bfu* wkv = (bfu*)(ws + 110100480);         // 67,108,864  (Wk rows 0-4095,
                                             //              Wv rows 4096-8191)
  bfu* Qb = (bfu*)(ws + 177209344);          // 67,108,864
  bfu* KVb = (bfu*)(ws + 244318208);         // 18,874,368  [1152][8192]
  bfu* Vt = (bfu*)(ws + 263192576);          //  9,437,184  -> total 272,629,760

  // fused front casts: hs, bp, Wq, Wk, Wv (all n8 divisible by 256)
  const int n8_hs = (int)(M1 * HIDn / 8);          // 4,194,304
  const int n8_bp = (int)(M2 * HIDn / 8);          //   589,824
  const int n8_w = (int)((long)HIDn * HIDn / 8);   // 2,097,152
  const long tot8 = (long)n8_hs + n8_bp + 3L * n8_w;
  cast5<<<dim3((int)(tot8 / 256)), dim3(256), 0, stream>>>(
      hs, hb, n8_hs, bp, bb, n8_bp, Wq, w1, n8_w, Wk, wkv, n8_w, Wv,
      wkv + (long)HIDn * HIDn, n8_w);

  gemm_bt256<1><<<dim3(HIDn / 256, M1 / 256), dim3(512), 0, stream>>>(
      hb, w1, Qb, (int)M1, HIDn, HIDn);
  // batched K+V projection: C[1152][8192] = bb @ [Wk;Wv]^T  (one dispatch)
  gemm_bt<1><<<dim3(8192 / 128, M2 / 128), dim3(256), 0, stream>>>(
      bb, wkv, KVb, (int)M2, 8192, HIDn);

  cast_f32_bf16<<<dim3(n8_w / 256), dim3(256), 0, stream>>>(
      Wo, w1, n8_w);  // w1 slot free after Q-proj
  transpose_v<<<dim3(NQn / 32, HDn / 32, Bn * Hn), dim3(256), 0, stream>>>(
      KVb, Vt);

  attn_kernel<<<dim3((Sn / 64) * Bn * Hn), dim3(256), 0, stream>>>(
      Qb, KVb, Vt, mask, hb /*AO aliases hb*/);

  gemm_bt256<0><<<dim3(HIDn / 256, M1 / 256), dim3(512), 0, stream>>>(
      hb, w1, out, (int)M1, HIDn, HIDn);
}